// Round 3
// baseline (4112.184 us; speedup 1.0000x reference)
//
#include <hip/hip_runtime.h>
#include <hip/hip_bf16.h>
#include <math.h>

// ---------------------------------------------------------------------------
// Problem constants (from reference)
// ---------------------------------------------------------------------------
#define IDIM   256
#define NU     512      // N_UNITS
#define NL     4        // N_LAYERS
#define EU     2048     // E_UNITS
#define NH     8        // heads
#define DK     64       // head dim
#define TT     1024     // seq len
#define NB     8        // batch (4*2)
#define MTOT   8192     // NB*TT tokens

typedef short  bf16x8 __attribute__((ext_vector_type(8)));
typedef float  f32x4  __attribute__((ext_vector_type(4)));
typedef unsigned short ushort8 __attribute__((ext_vector_type(8)));

// fp32 -> bf16 bits, round-to-nearest-even (data is finite/normal here)
__device__ __forceinline__ unsigned short f2b(float x) {
  unsigned int u = __float_as_uint(x);
  u += 0x7fffu + ((u >> 16) & 1u);
  return (unsigned short)(u >> 16);
}

// ---------------------------------------------------------------------------
// MFMA GEMM:  C[M,N] (+)= bf16(A[M,K]) @ bf16(W[N,K])^T + bias[N]  (opt ReLU)
// Both operands row-major K-contiguous (the "@ W.T" pattern) -> both load as
// the verified B^T fragment layout: lane holds 8 contiguous k at row lane&15,
// k-chunk lane>>4.  BM=BN=128, BK=32, 256 threads = 4 waves (2x2), each wave
// 64x64 via 4x4 fragments of v_mfma_f32_16x16x32_bf16.
// LDS row stride 40 elems (80B): rows 0..7 start banks {0,20,8,28,16,4,24,12}
// -> b128 reads tile all 32 banks, 2-way aliasing only (free).
// ---------------------------------------------------------------------------
template<bool ADD, bool RELU>
__global__ __launch_bounds__(256) void gemm_mfma(
    const float* __restrict__ A, const float* __restrict__ W,
    const float* __restrict__ bias, float* __restrict__ C,
    int M, int N, int K) {
  constexpr int BM = 128, BN = 128, BK = 32, LSTR = 40;
  __shared__ unsigned short As[BM * LSTR];
  __shared__ unsigned short Bs[BN * LSTR];

  const int tid  = threadIdx.x;
  const int lane = tid & 63;
  const int wave = tid >> 6;
  const int wm   = (wave >> 1) * 64;   // wave row offset in tile
  const int wn   = (wave & 1) * 64;    // wave col offset in tile
  const int fr   = lane & 15;          // fragment row (A) / col (B,C)
  const int fc   = lane >> 4;          // k-chunk (A,B) / row-group (C)

  const int m0 = blockIdx.y * BM;
  const int n0 = blockIdx.x * BN;

  // staging: thread t owns row t>>1 (of 128), k-half (t&1)*16 (of 32)
  const int sr = tid >> 1;
  const int sh = (tid & 1) * 16;
  const float* aptr = A + (size_t)(m0 + sr) * K + sh;
  const float* wptr = W + (size_t)(n0 + sr) * K + sh;
  unsigned short* asd = &As[sr * LSTR + sh];
  unsigned short* bsd = &Bs[sr * LSTR + sh];

  f32x4 acc[4][4];
#pragma unroll
  for (int i = 0; i < 4; ++i)
#pragma unroll
    for (int j = 0; j < 4; ++j) acc[i][j] = (f32x4){0.f, 0.f, 0.f, 0.f};

  for (int k0 = 0; k0 < K; k0 += BK) {
    // issue global loads early (fp32), convert to bf16 in regs
    float4 a0 = *(const float4*)(aptr + k0);
    float4 a1 = *(const float4*)(aptr + k0 + 4);
    float4 a2 = *(const float4*)(aptr + k0 + 8);
    float4 a3 = *(const float4*)(aptr + k0 + 12);
    float4 b0 = *(const float4*)(wptr + k0);
    float4 b1 = *(const float4*)(wptr + k0 + 4);
    float4 b2 = *(const float4*)(wptr + k0 + 8);
    float4 b3 = *(const float4*)(wptr + k0 + 12);

    ushort8 av0 = {f2b(a0.x), f2b(a0.y), f2b(a0.z), f2b(a0.w),
                   f2b(a1.x), f2b(a1.y), f2b(a1.z), f2b(a1.w)};
    ushort8 av1 = {f2b(a2.x), f2b(a2.y), f2b(a2.z), f2b(a2.w),
                   f2b(a3.x), f2b(a3.y), f2b(a3.z), f2b(a3.w)};
    ushort8 bv0 = {f2b(b0.x), f2b(b0.y), f2b(b0.z), f2b(b0.w),
                   f2b(b1.x), f2b(b1.y), f2b(b1.z), f2b(b1.w)};
    ushort8 bv1 = {f2b(b2.x), f2b(b2.y), f2b(b2.z), f2b(b2.w),
                   f2b(b3.x), f2b(b3.y), f2b(b3.z), f2b(b3.w)};

    __syncthreads();              // prior iteration's LDS reads complete
    *(ushort8*)(asd + 0) = av0;
    *(ushort8*)(asd + 8) = av1;
    *(ushort8*)(bsd + 0) = bv0;
    *(ushort8*)(bsd + 8) = bv1;
    __syncthreads();              // tile staged

    bf16x8 af[4], bf[4];
#pragma unroll
    for (int mi = 0; mi < 4; ++mi)
      af[mi] = *(const bf16x8*)&As[(wm + mi * 16 + fr) * LSTR + fc * 8];
#pragma unroll
    for (int ni = 0; ni < 4; ++ni)
      bf[ni] = *(const bf16x8*)&Bs[(wn + ni * 16 + fr) * LSTR + fc * 8];

#pragma unroll
    for (int mi = 0; mi < 4; ++mi)
#pragma unroll
      for (int ni = 0; ni < 4; ++ni)
        acc[mi][ni] = __builtin_amdgcn_mfma_f32_16x16x32_bf16(
            af[mi], bf[ni], acc[mi][ni], 0, 0, 0);
  }

  // epilogue: C/D layout col=lane&15, row=(lane>>4)*4+j (m89-verified)
#pragma unroll
  for (int ni = 0; ni < 4; ++ni) {
    const int col = n0 + wn + ni * 16 + fr;
    const float bb = bias[col];
#pragma unroll
    for (int mi = 0; mi < 4; ++mi) {
      const int row = m0 + wm + mi * 16 + fc * 4;
#pragma unroll
      for (int j = 0; j < 4; ++j) {
        size_t off = (size_t)(row + j) * N + col;
        float r = acc[mi][ni][j] + bb;
        if (RELU) r = fmaxf(r, 0.f);
        if (ADD)  r += C[off];
        C[off] = r;
      }
    }
  }
}

// ---------------------------------------------------------------------------
// In-place LayerNorm over rows of 512. One block (256 threads) per row.
// ---------------------------------------------------------------------------
__global__ __launch_bounds__(256) void layernorm_inplace(
    float* __restrict__ e, const float* __restrict__ g,
    const float* __restrict__ b) {
  const int row = blockIdx.x;
  float* x = e + (size_t)row * NU;
  const int tid = threadIdx.x;

  float2 v = *(const float2*)&x[tid * 2];
  float sum = v.x + v.y;
  float sq  = v.x * v.x + v.y * v.y;
#pragma unroll
  for (int o = 32; o > 0; o >>= 1) {
    sum += __shfl_down(sum, o);
    sq  += __shfl_down(sq, o);
  }
  __shared__ float ps[4], pq[4], stat[2];
  const int wid = tid >> 6, lane = tid & 63;
  if (lane == 0) { ps[wid] = sum; pq[wid] = sq; }
  __syncthreads();
  if (tid == 0) {
    float s = ps[0] + ps[1] + ps[2] + ps[3];
    float q = pq[0] + pq[1] + pq[2] + pq[3];
    float mu = s * (1.0f / NU);
    float var = q * (1.0f / NU) - mu * mu;
    stat[0] = mu;
    stat[1] = rsqrtf(var + 1e-5f);
  }
  __syncthreads();
  const float mu = stat[0], rstd = stat[1];
  const float2 gg = *(const float2*)&g[tid * 2];
  const float2 bb = *(const float2*)&b[tid * 2];
  v.x = (v.x - mu) * rstd * gg.x + bb.x;
  v.y = (v.y - mu) * rstd * gg.y + bb.y;
  *(float2*)&x[tid * 2] = v;
}

// ---------------------------------------------------------------------------
// Flash-style attention, fp32.  Layout: [B, T, H, DK] inside [MTOT, NU] bufs.
// Block = 256 threads handles (b, h, 32 query rows); loops 64-key tiles.
// ---------------------------------------------------------------------------
__global__ __launch_bounds__(256) void flash_attn(
    const float* __restrict__ Q, const float* __restrict__ K,
    const float* __restrict__ V, float* __restrict__ O) {
  constexpr int QT = 32, KT = 64, D = DK;
  __shared__ float Qs[QT][D + 1];
  __shared__ float Ks[KT][D + 1];
  __shared__ float Vs[KT][D + 1];
  __shared__ float Ss[QT][KT + 1];

  const int b = blockIdx.z, h = blockIdx.y;
  const int q0 = blockIdx.x * QT;
  const int tid = threadIdx.x;
  const size_t base = ((size_t)b * TT) * NU + h * D;
  const float scale = 0.125f;  // 1/sqrt(64)

  {  // load+scale Q tile (32x64)
    const int r = tid >> 3;
    const int c = (tid & 7) * 8;
    const float* src = Q + base + (size_t)(q0 + r) * NU + c;
    float4 v0 = *(const float4*)src;
    float4 v1 = *(const float4*)(src + 4);
    Qs[r][c + 0] = v0.x * scale; Qs[r][c + 1] = v0.y * scale;
    Qs[r][c + 2] = v0.z * scale; Qs[r][c + 3] = v0.w * scale;
    Qs[r][c + 4] = v1.x * scale; Qs[r][c + 5] = v1.y * scale;
    Qs[r][c + 6] = v1.z * scale; Qs[r][c + 7] = v1.w * scale;
  }

  float accv[8] = {};
  float m_i = -3e38f, l_i = 0.f;
  const int qr = tid & 31;             // PV phase: query row owned
  const int dg = (tid >> 5) * 8;       // PV phase: dim group owned
  const int sq = (tid & 7) * 4;        // score phase: 4 q rows
  const int sk = (tid >> 3) * 2;       // score phase: 2 keys

  for (int kt = 0; kt < TT; kt += KT) {
    __syncthreads();  // prev tile's Ss/Vs reads done
    {  // load K,V tile (64x64 each)
      const int r = tid >> 2;
      const int c = (tid & 3) * 16;
      const float* ksrc = K + base + (size_t)(kt + r) * NU + c;
      const float* vsrc = V + base + (size_t)(kt + r) * NU + c;
#pragma unroll
      for (int j = 0; j < 4; ++j) {
        float4 kv = *(const float4*)(ksrc + j * 4);
        float4 vv = *(const float4*)(vsrc + j * 4);
        Ks[r][c + j * 4 + 0] = kv.x; Ks[r][c + j * 4 + 1] = kv.y;
        Ks[r][c + j * 4 + 2] = kv.z; Ks[r][c + j * 4 + 3] = kv.w;
        Vs[r][c + j * 4 + 0] = vv.x; Vs[r][c + j * 4 + 1] = vv.y;
        Vs[r][c + j * 4 + 2] = vv.z; Vs[r][c + j * 4 + 3] = vv.w;
      }
    }
    __syncthreads();

    // scores: each thread 4 q-rows x 2 keys
    float s00 = 0, s01 = 0, s10 = 0, s11 = 0, s20 = 0, s21 = 0, s30 = 0, s31 = 0;
#pragma unroll 8
    for (int d = 0; d < D; ++d) {
      float k0v = Ks[sk][d], k1v = Ks[sk + 1][d];
      float q0v = Qs[sq + 0][d], q1v = Qs[sq + 1][d];
      float q2v = Qs[sq + 2][d], q3v = Qs[sq + 3][d];
      s00 += q0v * k0v; s01 += q0v * k1v;
      s10 += q1v * k0v; s11 += q1v * k1v;
      s20 += q2v * k0v; s21 += q2v * k1v;
      s30 += q3v * k0v; s31 += q3v * k1v;
    }
    Ss[sq + 0][sk] = s00; Ss[sq + 0][sk + 1] = s01;
    Ss[sq + 1][sk] = s10; Ss[sq + 1][sk + 1] = s11;
    Ss[sq + 2][sk] = s20; Ss[sq + 2][sk + 1] = s21;
    Ss[sq + 3][sk] = s30; Ss[sq + 3][sk + 1] = s31;
    __syncthreads();

    // online softmax + PV for owned (qr, dg)
    float tmax = -3e38f;
#pragma unroll 8
    for (int k = 0; k < KT; ++k) tmax = fmaxf(tmax, Ss[qr][k]);
    float m_new = fmaxf(m_i, tmax);
    float corr = __expf(m_i - m_new);
    l_i *= corr;
#pragma unroll
    for (int j = 0; j < 8; ++j) accv[j] *= corr;
#pragma unroll 4
    for (int k = 0; k < KT; ++k) {
      float p = __expf(Ss[qr][k] - m_new);
      l_i += p;
#pragma unroll
      for (int j = 0; j < 8; ++j) accv[j] += p * Vs[k][dg + j];
    }
    m_i = m_new;
  }

  const float inv = 1.0f / l_i;
  float* dst = O + base + (size_t)(q0 + qr) * NU + dg;
  float4 o0 = {accv[0] * inv, accv[1] * inv, accv[2] * inv, accv[3] * inv};
  float4 o1 = {accv[4] * inv, accv[5] * inv, accv[6] * inv, accv[7] * inv};
  *(float4*)dst = o0;
  *(float4*)(dst + 4) = o1;
}

// ---------------------------------------------------------------------------
// Launcher
// ---------------------------------------------------------------------------
extern "C" void kernel_launch(void* const* d_in, const int* in_sizes, int n_in,
                              void* d_out, int out_size, void* d_ws, size_t ws_size,
                              hipStream_t stream) {
  const float* x     = (const float*)d_in[0];
  const float* Win   = (const float*)d_in[1];
  const float* bin_  = (const float*)d_in[2];
  const float* ln1_g = (const float*)d_in[3];
  const float* ln1_b = (const float*)d_in[4];
  const float* Wq    = (const float*)d_in[5];
  const float* bq    = (const float*)d_in[6];
  const float* Wk    = (const float*)d_in[7];
  const float* bk    = (const float*)d_in[8];
  const float* Wv    = (const float*)d_in[9];
  const float* bv    = (const float*)d_in[10];
  const float* Wo    = (const float*)d_in[11];
  const float* bo    = (const float*)d_in[12];
  const float* ln2_g = (const float*)d_in[13];
  const float* ln2_b = (const float*)d_in[14];
  const float* W1    = (const float*)d_in[15];
  const float* b1    = (const float*)d_in[16];
  const float* W2    = (const float*)d_in[17];
  const float* b2    = (const float*)d_in[18];
  const float* lno_g = (const float*)d_in[19];
  const float* lno_b = (const float*)d_in[20];

  float* e = (float*)d_out;             // activation lives in d_out (8192x512)
  float* ws = (float*)d_ws;
  const size_t SLOT = (size_t)MTOT * NU;  // 4M floats = 16MB
  float* q   = ws;
  float* k   = ws + SLOT;
  float* v   = ws + 2 * SLOT;
  float* ctx = ws + 3 * SLOT;
  float* hdn = ws;                      // 4096x2048 = 8M floats, reuses q+k slots

  const dim3 blk(256);
  const dim3 gProjIn(NU / 128, MTOT / 128);   // (4,64)
  const dim3 gQKV(NU / 128, MTOT / 128);      // (4,64)
  const dim3 gF1(EU / 128, 4096 / 128);       // (16,32)
  const dim3 gF2(NU / 128, 4096 / 128);       // (4,32)
  const dim3 gAttn(TT / 32, NH, NB);          // (32,8,8)

  // input projection: e = x @ Win^T + bin
  gemm_mfma<false, false><<<gProjIn, blk, 0, stream>>>(x, Win, bin_, e, MTOT, NU, IDIM);

  for (int i = 0; i < NL; ++i) {
    const float* wq = Wq + (size_t)i * NU * NU;
    const float* wk = Wk + (size_t)i * NU * NU;
    const float* wv = Wv + (size_t)i * NU * NU;
    const float* wo = Wo + (size_t)i * NU * NU;
    const float* w1 = W1 + (size_t)i * EU * NU;
    const float* w2 = W2 + (size_t)i * NU * EU;

    // e = LN1(e)  (in place)
    layernorm_inplace<<<MTOT, blk, 0, stream>>>(e, ln1_g + i * NU, ln1_b + i * NU);

    // q,k,v projections
    gemm_mfma<false, false><<<gQKV, blk, 0, stream>>>(e, wq, bq + i * NU, q, MTOT, NU, NU);
    gemm_mfma<false, false><<<gQKV, blk, 0, stream>>>(e, wk, bk + i * NU, k, MTOT, NU, NU);
    gemm_mfma<false, false><<<gQKV, blk, 0, stream>>>(e, wv, bv + i * NU, v, MTOT, NU, NU);

    // attention -> ctx
    flash_attn<<<gAttn, blk, 0, stream>>>(q, k, v, ctx);

    // e += ctx @ Wo^T + bo
    gemm_mfma<true, false><<<gQKV, blk, 0, stream>>>(ctx, wo, bo + i * NU, e, MTOT, NU, NU);

    // e = LN2(e)
    layernorm_inplace<<<MTOT, blk, 0, stream>>>(e, ln2_g + i * NU, ln2_b + i * NU);

    // FFN in two row-chunks of 4096 (hdn reuses q+k workspace slots)
    for (int c = 0; c < 2; ++c) {
      float* ec = e + (size_t)c * 4096 * NU;
      gemm_mfma<false, true><<<gF1, blk, 0, stream>>>(ec, w1, b1 + i * EU, hdn, 4096, EU, NU);
      gemm_mfma<true, false><<<gF2, blk, 0, stream>>>(hdn, w2, b2 + i * NU, ec, 4096, NU, EU);
    }
  }

  // final LN (in place on d_out)
  layernorm_inplace<<<MTOT, blk, 0, stream>>>(e, lno_g, lno_b);
}

// Round 5
// 2003.218 us; speedup vs baseline: 2.0528x; 2.0528x over previous
//
#include <hip/hip_runtime.h>
#include <hip/hip_bf16.h>
#include <math.h>

// ---------------------------------------------------------------------------
// Problem constants (from reference)
// ---------------------------------------------------------------------------
#define IDIM   256
#define NU     512      // N_UNITS
#define NL     4        // N_LAYERS
#define EU     2048     // E_UNITS
#define NH     8        // heads
#define DK     64       // head dim
#define TT     1024     // seq len
#define NB     8        // batch (4*2)
#define MTOT   8192     // NB*TT tokens

typedef short  bf16x8 __attribute__((ext_vector_type(8)));
typedef float  f32x4  __attribute__((ext_vector_type(4)));
typedef unsigned short ushort8 __attribute__((ext_vector_type(8)));

// fp32 -> bf16 bits, round-to-nearest-even (data is finite/normal here)
__device__ __forceinline__ unsigned short f2b(float x) {
  unsigned int u = __float_as_uint(x);
  u += 0x7fffu + ((u >> 16) & 1u);
  return (unsigned short)(u >> 16);
}

__device__ __forceinline__ bf16x8 cvt8(float4 a, float4 b, float s) {
  bf16x8 r;
  r[0] = (short)f2b(a.x * s); r[1] = (short)f2b(a.y * s);
  r[2] = (short)f2b(a.z * s); r[3] = (short)f2b(a.w * s);
  r[4] = (short)f2b(b.x * s); r[5] = (short)f2b(b.y * s);
  r[6] = (short)f2b(b.z * s); r[7] = (short)f2b(b.w * s);
  return r;
}

// ---------------------------------------------------------------------------
// MFMA GEMM:  C[M,N] (+)= bf16(A[M,K]) @ bf16(W[N,K])^T + bias[N]  (opt ReLU)
// BM=BN=128, BK=32, 256 threads = 4 waves (2x2), 4x4 16x16x32 frags per wave.
// ---------------------------------------------------------------------------
template<bool ADD, bool RELU>
__global__ __launch_bounds__(256) void gemm_mfma(
    const float* __restrict__ A, const float* __restrict__ W,
    const float* __restrict__ bias, float* __restrict__ C,
    int M, int N, int K) {
  constexpr int BM = 128, BN = 128, BK = 32, LSTR = 40;
  __shared__ unsigned short As[BM * LSTR];
  __shared__ unsigned short Bs[BN * LSTR];

  const int tid  = threadIdx.x;
  const int lane = tid & 63;
  const int wave = tid >> 6;
  const int wm   = (wave >> 1) * 64;   // wave row offset in tile
  const int wn   = (wave & 1) * 64;    // wave col offset in tile
  const int fr   = lane & 15;          // fragment row (A) / col (B,C)
  const int fc   = lane >> 4;          // k-chunk (A,B) / row-group (C)

  const int m0 = blockIdx.y * BM;
  const int n0 = blockIdx.x * BN;

  const int sr = tid >> 1;
  const int sh = (tid & 1) * 16;
  const float* aptr = A + (size_t)(m0 + sr) * K + sh;
  const float* wptr = W + (size_t)(n0 + sr) * K + sh;
  unsigned short* asd = &As[sr * LSTR + sh];
  unsigned short* bsd = &Bs[sr * LSTR + sh];

  f32x4 acc[4][4];
#pragma unroll
  for (int i = 0; i < 4; ++i)
#pragma unroll
    for (int j = 0; j < 4; ++j) acc[i][j] = (f32x4){0.f, 0.f, 0.f, 0.f};

  for (int k0 = 0; k0 < K; k0 += BK) {
    float4 a0 = *(const float4*)(aptr + k0);
    float4 a1 = *(const float4*)(aptr + k0 + 4);
    float4 a2 = *(const float4*)(aptr + k0 + 8);
    float4 a3 = *(const float4*)(aptr + k0 + 12);
    float4 b0 = *(const float4*)(wptr + k0);
    float4 b1 = *(const float4*)(wptr + k0 + 4);
    float4 b2 = *(const float4*)(wptr + k0 + 8);
    float4 b3 = *(const float4*)(wptr + k0 + 12);

    bf16x8 av0 = cvt8(a0, a1, 1.f), av1 = cvt8(a2, a3, 1.f);
    bf16x8 bv0 = cvt8(b0, b1, 1.f), bv1 = cvt8(b2, b3, 1.f);

    __syncthreads();
    *(bf16x8*)(asd + 0) = av0;
    *(bf16x8*)(asd + 8) = av1;
    *(bf16x8*)(bsd + 0) = bv0;
    *(bf16x8*)(bsd + 8) = bv1;
    __syncthreads();

    bf16x8 af[4], bf[4];
#pragma unroll
    for (int mi = 0; mi < 4; ++mi)
      af[mi] = *(const bf16x8*)&As[(wm + mi * 16 + fr) * LSTR + fc * 8];
#pragma unroll
    for (int ni = 0; ni < 4; ++ni)
      bf[ni] = *(const bf16x8*)&Bs[(wn + ni * 16 + fr) * LSTR + fc * 8];

#pragma unroll
    for (int mi = 0; mi < 4; ++mi)
#pragma unroll
      for (int ni = 0; ni < 4; ++ni)
        acc[mi][ni] = __builtin_amdgcn_mfma_f32_16x16x32_bf16(
            af[mi], bf[ni], acc[mi][ni], 0, 0, 0);
  }

#pragma unroll
  for (int ni = 0; ni < 4; ++ni) {
    const int col = n0 + wn + ni * 16 + fr;
    const float bb = bias[col];
#pragma unroll
    for (int mi = 0; mi < 4; ++mi) {
      const int row = m0 + wm + mi * 16 + fc * 4;
#pragma unroll
      for (int j = 0; j < 4; ++j) {
        size_t off = (size_t)(row + j) * N + col;
        float r = acc[mi][ni][j] + bb;
        if (RELU) r = fmaxf(r, 0.f);
        if (ADD)  r += C[off];
        C[off] = r;
      }
    }
  }
}

// ---------------------------------------------------------------------------
// In-place LayerNorm over rows of 512. One block (256 threads) per row.
// ---------------------------------------------------------------------------
__global__ __launch_bounds__(256) void layernorm_inplace(
    float* __restrict__ e, const float* __restrict__ g,
    const float* __restrict__ b) {
  const int row = blockIdx.x;
  float* x = e + (size_t)row * NU;
  const int tid = threadIdx.x;

  float2 v = *(const float2*)&x[tid * 2];
  float sum = v.x + v.y;
  float sq  = v.x * v.x + v.y * v.y;
#pragma unroll
  for (int o = 32; o > 0; o >>= 1) {
    sum += __shfl_down(sum, o);
    sq  += __shfl_down(sq, o);
  }
  __shared__ float ps[4], pq[4], stat[2];
  const int wid = tid >> 6, lane = tid & 63;
  if (lane == 0) { ps[wid] = sum; pq[wid] = sq; }
  __syncthreads();
  if (tid == 0) {
    float s = ps[0] + ps[1] + ps[2] + ps[3];
    float q = pq[0] + pq[1] + pq[2] + pq[3];
    float mu = s * (1.0f / NU);
    float var = q * (1.0f / NU) - mu * mu;
    stat[0] = mu;
    stat[1] = rsqrtf(var + 1e-5f);
  }
  __syncthreads();
  const float mu = stat[0], rstd = stat[1];
  const float2 gg = *(const float2*)&g[tid * 2];
  const float2 bb = *(const float2*)&b[tid * 2];
  v.x = (v.x - mu) * rstd * gg.x + bb.x;
  v.y = (v.y - mu) * rstd * gg.y + bb.y;
  *(float2*)&x[tid * 2] = v;
}

// ---------------------------------------------------------------------------
// MFMA flash attention (bf16 compute, fp32 accumulate).
// Layout: [B, T, H, DK] inside [MTOT, NU] buffers.
// Block = 4 waves, each wave owns 32 q-rows (128 q-rows/block).
// Per 64-key tile: QK^T via 16 MFMAs, online softmax on C-layout accs,
// P -> LDS (bf16) -> A-fragments, PV via 16 MFMAs with V staged transposed.
// All LDS row strides = 72 elems (144B, 16B-aligned).
// ---------------------------------------------------------------------------
__global__ __launch_bounds__(256) void flash_attn_mfma(
    const float* __restrict__ Q, const float* __restrict__ K,
    const float* __restrict__ V, float* __restrict__ O) {
  constexpr int LSTR = 72;
  __shared__ unsigned short Ks[64 * LSTR];   // [k][d]
  __shared__ unsigned short Vt[64 * LSTR];   // [d][k]  (transposed)
  __shared__ unsigned short Ps[128 * LSTR];  // [q][k], rows 32w..32w+31 per wave

  const int b = blockIdx.z, h = blockIdx.y;
  const int q0 = blockIdx.x * 128;
  const int tid = threadIdx.x;
  const int lane = tid & 63;
  const int w = tid >> 6;
  const int fr = lane & 15;
  const int fc = lane >> 4;

  const size_t hb = ((size_t)b * TT) * NU + h * DK;

  // Q fragments in regs, pre-scaled by 1/8 (exact in bf16)
  bf16x8 qf[2][2];
#pragma unroll
  for (int mi = 0; mi < 2; ++mi)
#pragma unroll
    for (int kc = 0; kc < 2; ++kc) {
      const float* qs = Q + hb + (size_t)(q0 + w * 32 + mi * 16 + fr) * NU + kc * 32 + fc * 8;
      float4 x0 = *(const float4*)qs;
      float4 x1 = *(const float4*)(qs + 4);
      qf[mi][kc] = cvt8(x0, x1, 0.125f);
    }

  f32x4 ctx[2][4];
#pragma unroll
  for (int mi = 0; mi < 2; ++mi)
#pragma unroll
    for (int ni = 0; ni < 4; ++ni) ctx[mi][ni] = (f32x4){0.f, 0.f, 0.f, 0.f};
  float m_run[2][4], l_run[2][4];
#pragma unroll
  for (int mi = 0; mi < 2; ++mi)
#pragma unroll
    for (int j = 0; j < 4; ++j) { m_run[mi][j] = -1e30f; l_run[mi][j] = 0.f; }

  // staging assignment: thread -> (row sr, 16-col chunk sd)
  const int sr = tid >> 2;
  const int sd = (tid & 3) * 16;

  for (int kt = 0; kt < TT; kt += 64) {
    const float* kp = K + hb + (size_t)(kt + sr) * NU + sd;
    const float* vp = V + hb + (size_t)(kt + sr) * NU + sd;
    float4 k0 = *(const float4*)kp,       k1 = *(const float4*)(kp + 4);
    float4 k2 = *(const float4*)(kp + 8), k3 = *(const float4*)(kp + 12);
    float4 v0 = *(const float4*)vp,       v1 = *(const float4*)(vp + 4);
    float4 v2 = *(const float4*)(vp + 8), v3 = *(const float4*)(vp + 12);

    __syncthreads();   // everyone done reading Ks/Vt of previous tile
    *(bf16x8*)&Ks[sr * LSTR + sd]     = cvt8(k0, k1, 1.f);
    *(bf16x8*)&Ks[sr * LSTR + sd + 8] = cvt8(k2, k3, 1.f);
    {  // transpose V into Vt
      float vv[16];
      *(float4*)&vv[0]  = v0; *(float4*)&vv[4]  = v1;
      *(float4*)&vv[8]  = v2; *(float4*)&vv[12] = v3;
#pragma unroll
      for (int t = 0; t < 16; ++t)
        Vt[(sd + t) * LSTR + sr] = f2b(vv[t]);
    }
    __syncthreads();   // tile staged

    // ---- QK^T ----
    bf16x8 kf[4][2];
#pragma unroll
    for (int ni = 0; ni < 4; ++ni)
#pragma unroll
      for (int kc = 0; kc < 2; ++kc)
        kf[ni][kc] = *(const bf16x8*)&Ks[(ni * 16 + fr) * LSTR + kc * 32 + fc * 8];

    f32x4 sacc[2][4];
#pragma unroll
    for (int mi = 0; mi < 2; ++mi)
#pragma unroll
      for (int ni = 0; ni < 4; ++ni) sacc[mi][ni] = (f32x4){0.f, 0.f, 0.f, 0.f};
#pragma unroll
    for (int kc = 0; kc < 2; ++kc)
#pragma unroll
      for (int mi = 0; mi < 2; ++mi)
#pragma unroll
        for (int ni = 0; ni < 4; ++ni)
          sacc[mi][ni] = __builtin_amdgcn_mfma_f32_16x16x32_bf16(
              qf[mi][kc], kf[ni][kc], sacc[mi][ni], 0, 0, 0);

    // ---- online softmax (C-layout: col=fr across 16 lanes, row=fc*4+j) ----
#pragma unroll
    for (int mi = 0; mi < 2; ++mi) {
      float cm[4];
#pragma unroll
      for (int j = 0; j < 4; ++j)
        cm[j] = fmaxf(fmaxf(sacc[mi][0][j], sacc[mi][1][j]),
                      fmaxf(sacc[mi][2][j], sacc[mi][3][j]));
#pragma unroll
      for (int mask = 1; mask < 16; mask <<= 1)
#pragma unroll
        for (int j = 0; j < 4; ++j)
          cm[j] = fmaxf(cm[j], __shfl_xor(cm[j], mask));
#pragma unroll
      for (int j = 0; j < 4; ++j) {
        float mn = fmaxf(m_run[mi][j], cm[j]);
        float corr = __expf(m_run[mi][j] - mn);
        m_run[mi][j] = mn;
        l_run[mi][j] *= corr;
#pragma unroll
        for (int ni = 0; ni < 4; ++ni) {
          ctx[mi][ni][j] *= corr;
          float p = __expf(sacc[mi][ni][j] - mn);
          l_run[mi][j] += p;           // lane-partial row sum (reduced at end)
          Ps[(w * 32 + mi * 16 + fc * 4 + j) * LSTR + ni * 16 + fr] = f2b(p);
        }
      }
    }

    // ---- PV ----  (Ps rows are wave-private; in-wave ds ordering suffices)
    bf16x8 pf[2][2], vf[4][2];
#pragma unroll
    for (int mi = 0; mi < 2; ++mi)
#pragma unroll
      for (int kc = 0; kc < 2; ++kc)
        pf[mi][kc] = *(const bf16x8*)&Ps[(w * 32 + mi * 16 + fr) * LSTR + kc * 32 + fc * 8];
#pragma unroll
    for (int ni = 0; ni < 4; ++ni)
#pragma unroll
      for (int kc = 0; kc < 2; ++kc)
        vf[ni][kc] = *(const bf16x8*)&Vt[(ni * 16 + fr) * LSTR + kc * 32 + fc * 8];
#pragma unroll
    for (int kc = 0; kc < 2; ++kc)
#pragma unroll
      for (int mi = 0; mi < 2; ++mi)
#pragma unroll
        for (int ni = 0; ni < 4; ++ni)
          ctx[mi][ni] = __builtin_amdgcn_mfma_f32_16x16x32_bf16(
              pf[mi][kc], vf[ni][kc], ctx[mi][ni], 0, 0, 0);
  }

  // ---- epilogue: reduce l across the 16 lanes of each row, write O ----
#pragma unroll
  for (int mi = 0; mi < 2; ++mi)
#pragma unroll
    for (int j = 0; j < 4; ++j) {
      float l = l_run[mi][j];
#pragma unroll
      for (int mask = 1; mask < 16; mask <<= 1)
        l += __shfl_xor(l, mask);
      const float inv = 1.0f / l;
      const int row = q0 + w * 32 + mi * 16 + fc * 4 + j;
      float* dst = O + hb + (size_t)row * NU;
#pragma unroll
      for (int ni = 0; ni < 4; ++ni)
        dst[ni * 16 + fr] = ctx[mi][ni][j] * inv;
    }
}

// ---------------------------------------------------------------------------
// Launcher
// ---------------------------------------------------------------------------
extern "C" void kernel_launch(void* const* d_in, const int* in_sizes, int n_in,
                              void* d_out, int out_size, void* d_ws, size_t ws_size,
                              hipStream_t stream) {
  const float* x     = (const float*)d_in[0];
  const float* Win   = (const float*)d_in[1];
  const float* bin_  = (const float*)d_in[2];
  const float* ln1_g = (const float*)d_in[3];
  const float* ln1_b = (const float*)d_in[4];
  const float* Wq    = (const float*)d_in[5];
  const float* bq    = (const float*)d_in[6];
  const float* Wk    = (const float*)d_in[7];
  const float* bk    = (const float*)d_in[8];
  const float* Wv    = (const float*)d_in[9];
  const float* bv    = (const float*)d_in[10];
  const float* Wo    = (const float*)d_in[11];
  const float* bo    = (const float*)d_in[12];
  const float* ln2_g = (const float*)d_in[13];
  const float* ln2_b = (const float*)d_in[14];
  const float* W1    = (const float*)d_in[15];
  const float* b1    = (const float*)d_in[16];
  const float* W2    = (const float*)d_in[17];
  const float* b2    = (const float*)d_in[18];
  const float* lno_g = (const float*)d_in[19];
  const float* lno_b = (const float*)d_in[20];

  float* e = (float*)d_out;             // activation lives in d_out (8192x512)
  float* ws = (float*)d_ws;
  const size_t SLOT = (size_t)MTOT * NU;  // 4M floats = 16MB
  float* q   = ws;
  float* k   = ws + SLOT;
  float* v   = ws + 2 * SLOT;
  float* ctx = ws + 3 * SLOT;
  float* hdn = ws;                      // 4096x2048 = 8M floats, reuses q+k slots

  const dim3 blk(256);
  const dim3 gProjIn(NU / 128, MTOT / 128);   // (4,64)
  const dim3 gQKV(NU / 128, MTOT / 128);      // (4,64)
  const dim3 gF1(EU / 128, 4096 / 128);       // (16,32)
  const dim3 gF2(NU / 128, 4096 / 128);       // (4,32)
  const dim3 gAttn(TT / 128, NH, NB);         // (8,8,8)

  // input projection: e = x @ Win^T + bin
  gemm_mfma<false, false><<<gProjIn, blk, 0, stream>>>(x, Win, bin_, e, MTOT, NU, IDIM);

  for (int i = 0; i < NL; ++i) {
    const float* wq = Wq + (size_t)i * NU * NU;
    const float* wk = Wk + (size_t)i * NU * NU;
    const float* wv = Wv + (size_t)i * NU * NU;
    const float* wo = Wo + (size_t)i * NU * NU;
    const float* w1 = W1 + (size_t)i * EU * NU;
    const float* w2 = W2 + (size_t)i * NU * EU;

    // e = LN1(e)  (in place)
    layernorm_inplace<<<MTOT, blk, 0, stream>>>(e, ln1_g + i * NU, ln1_b + i * NU);

    // q,k,v projections
    gemm_mfma<false, false><<<gQKV, blk, 0, stream>>>(e, wq, bq + i * NU, q, MTOT, NU, NU);
    gemm_mfma<false, false><<<gQKV, blk, 0, stream>>>(e, wk, bk + i * NU, k, MTOT, NU, NU);
    gemm_mfma<false, false><<<gQKV, blk, 0, stream>>>(e, wv, bv + i * NU, v, MTOT, NU, NU);

    // attention -> ctx
    flash_attn_mfma<<<gAttn, blk, 0, stream>>>(q, k, v, ctx);

    // e += ctx @ Wo^T + bo
    gemm_mfma<true, false><<<gQKV, blk, 0, stream>>>(ctx, wo, bo + i * NU, e, MTOT, NU, NU);

    // e = LN2(e)
    layernorm_inplace<<<MTOT, blk, 0, stream>>>(e, ln2_g + i * NU, ln2_b + i * NU);

    // FFN in two row-chunks of 4096 (hdn reuses q+k workspace slots)
    for (int c = 0; c < 2; ++c) {
      float* ec = e + (size_t)c * 4096 * NU;
      gemm_mfma<false, true><<<gF1, blk, 0, stream>>>(ec, w1, b1 + i * EU, hdn, 4096, EU, NU);
      gemm_mfma<true, false><<<gF2, blk, 0, stream>>>(hdn, w2, b2 + i * NU, ec, 4096, NU, EU);
    }
  }

  // final LN (in place on d_out)
  layernorm_inplace<<<MTOT, blk, 0, stream>>>(e, lno_g, lno_b);
}

// Round 6
// 1399.897 us; speedup vs baseline: 2.9375x; 1.4310x over previous
//
#include <hip/hip_runtime.h>
#include <hip/hip_bf16.h>
#include <math.h>

// ---------------------------------------------------------------------------
// Problem constants (from reference)
// ---------------------------------------------------------------------------
#define IDIM   256
#define NU     512      // N_UNITS
#define NL     4        // N_LAYERS
#define EU     2048     // E_UNITS
#define NH     8        // heads
#define DK     64       // head dim
#define TT     1024     // seq len
#define NB     8        // batch (4*2)
#define MTOT   8192     // NB*TT tokens

typedef short  bf16x8 __attribute__((ext_vector_type(8)));
typedef float  f32x4  __attribute__((ext_vector_type(4)));

// fp32 -> bf16 bits, round-to-nearest-even
__device__ __forceinline__ unsigned short f2b(float x) {
  unsigned int u = __float_as_uint(x);
  u += 0x7fffu + ((u >> 16) & 1u);
  return (unsigned short)(u >> 16);
}

__device__ __forceinline__ bf16x8 cvt8(float4 a, float4 b, float s) {
  bf16x8 r;
  r[0] = (short)f2b(a.x * s); r[1] = (short)f2b(a.y * s);
  r[2] = (short)f2b(a.z * s); r[3] = (short)f2b(a.w * s);
  r[4] = (short)f2b(b.x * s); r[5] = (short)f2b(b.y * s);
  r[6] = (short)f2b(b.z * s); r[7] = (short)f2b(b.w * s);
  return r;
}

// ---------------------------------------------------------------------------
// Shared GEMM tile body pieces (BM=BN=128, BK=32, 4 waves 2x2, 4x4 frags).
// LDS row stride 40 shorts (80B).
// ---------------------------------------------------------------------------
#define GEMM_PROLOGUE(K_)                                                    \
  constexpr int LSTR = 40;                                                   \
  __shared__ unsigned short As[128 * LSTR];                                  \
  __shared__ unsigned short Bs[128 * LSTR];                                  \
  const int tid  = threadIdx.x;                                              \
  const int lane = tid & 63;                                                 \
  const int wave = tid >> 6;                                                 \
  const int wm   = (wave >> 1) * 64;                                         \
  const int wn   = (wave & 1) * 64;                                          \
  const int fr   = lane & 15;                                                \
  const int fc   = lane >> 4;                                                \
  const int sr = tid >> 1;                                                   \
  const int sh = (tid & 1) * 16;                                             \
  const float* aptr = A + (size_t)(m0 + sr) * (K_) + sh;                     \
  const float* wptr = W + (size_t)(n0 + sr) * (K_) + sh;                     \
  unsigned short* asd = &As[sr * LSTR + sh];                                 \
  unsigned short* bsd = &Bs[sr * LSTR + sh];                                 \
  f32x4 acc[4][4];                                                           \
  _Pragma("unroll") for (int i = 0; i < 4; ++i)                              \
    _Pragma("unroll") for (int j = 0; j < 4; ++j)                            \
      acc[i][j] = (f32x4){0.f, 0.f, 0.f, 0.f};

#define GEMM_KSTEP(k0)                                                       \
  {                                                                          \
    float4 a0 = *(const float4*)(aptr + (k0));                               \
    float4 a1 = *(const float4*)(aptr + (k0) + 4);                           \
    float4 a2 = *(const float4*)(aptr + (k0) + 8);                           \
    float4 a3 = *(const float4*)(aptr + (k0) + 12);                          \
    float4 b0 = *(const float4*)(wptr + (k0));                               \
    float4 b1 = *(const float4*)(wptr + (k0) + 4);                           \
    float4 b2 = *(const float4*)(wptr + (k0) + 8);                           \
    float4 b3 = *(const float4*)(wptr + (k0) + 12);                          \
    bf16x8 av0 = cvt8(a0, a1, 1.f), av1 = cvt8(a2, a3, 1.f);                 \
    bf16x8 bv0 = cvt8(b0, b1, 1.f), bv1 = cvt8(b2, b3, 1.f);                 \
    __syncthreads();                                                         \
    *(bf16x8*)(asd + 0) = av0;                                               \
    *(bf16x8*)(asd + 8) = av1;                                               \
    *(bf16x8*)(bsd + 0) = bv0;                                               \
    *(bf16x8*)(bsd + 8) = bv1;                                               \
    __syncthreads();                                                         \
    bf16x8 af[4], bf[4];                                                     \
    _Pragma("unroll") for (int mi = 0; mi < 4; ++mi)                         \
      af[mi] = *(const bf16x8*)&As[(wm + mi * 16 + fr) * LSTR + fc * 8];     \
    _Pragma("unroll") for (int ni = 0; ni < 4; ++ni)                         \
      bf[ni] = *(const bf16x8*)&Bs[(wn + ni * 16 + fr) * LSTR + fc * 8];     \
    _Pragma("unroll") for (int mi = 0; mi < 4; ++mi)                         \
      _Pragma("unroll") for (int ni = 0; ni < 4; ++ni)                       \
        acc[mi][ni] = __builtin_amdgcn_mfma_f32_16x16x32_bf16(               \
            af[mi], bf[ni], acc[mi][ni], 0, 0, 0);                           \
  }

// ---------------------------------------------------------------------------
// Plain GEMM:  C[M,N] = bf16(A) @ bf16(W)^T + bias  (opt ReLU)
// ---------------------------------------------------------------------------
template<bool RELU>
__global__ __launch_bounds__(256) void gemm_mfma(
    const float* __restrict__ A, const float* __restrict__ W,
    const float* __restrict__ bias, float* __restrict__ C,
    int M, int N, int K) {
  const int m0 = blockIdx.y * 128;
  const int n0 = blockIdx.x * 128;
  GEMM_PROLOGUE(K)
  for (int k0 = 0; k0 < K; k0 += 32) GEMM_KSTEP(k0)

#pragma unroll
  for (int ni = 0; ni < 4; ++ni) {
    const int col = n0 + wn + ni * 16 + fr;
    const float bb = bias[col];
#pragma unroll
    for (int mi = 0; mi < 4; ++mi) {
      const int row = m0 + wm + mi * 16 + fc * 4;
#pragma unroll
      for (int j = 0; j < 4; ++j) {
        size_t off = (size_t)(row + j) * N + col;
        float r = acc[mi][ni][j] + bb;
        if (RELU) r = fmaxf(r, 0.f);
        C[off] = r;
      }
    }
  }
}

// ---------------------------------------------------------------------------
// Fused QKV: blockIdx.z picks (W, bias, out).  M=MTOT, N=NU, K=NU.
// ---------------------------------------------------------------------------
__global__ __launch_bounds__(256) void gemm_qkv(
    const float* __restrict__ A,
    const float* __restrict__ Wq, const float* __restrict__ Wk,
    const float* __restrict__ Wv,
    const float* __restrict__ bq, const float* __restrict__ bk,
    const float* __restrict__ bv,
    float* __restrict__ Oq, float* __restrict__ Ok, float* __restrict__ Ov) {
  const int zz = blockIdx.z;
  const float* W    = zz == 0 ? Wq : (zz == 1 ? Wk : Wv);
  const float* bias = zz == 0 ? bq : (zz == 1 ? bk : bv);
  float*       C    = zz == 0 ? Oq : (zz == 1 ? Ok : Ov);
  const int m0 = blockIdx.y * 128;
  const int n0 = blockIdx.x * 128;
  GEMM_PROLOGUE(NU)
#pragma unroll 1
  for (int k0 = 0; k0 < NU; k0 += 32) GEMM_KSTEP(k0)

#pragma unroll
  for (int ni = 0; ni < 4; ++ni) {
    const int col = n0 + wn + ni * 16 + fr;
    const float bb = bias[col];
#pragma unroll
    for (int mi = 0; mi < 4; ++mi) {
      const int row = m0 + wm + mi * 16 + fc * 4;
#pragma unroll
      for (int j = 0; j < 4; ++j)
        C[(size_t)(row + j) * NU + col] = acc[mi][ni][j] + bb;
    }
  }
}

// ---------------------------------------------------------------------------
// Split-K GEMM with atomic accumulate:  C += partial(A@W^T) (+bias once).
// blockIdx.z = K-chunk.  Residual must already be in C.  No ReLU.
// ---------------------------------------------------------------------------
template<int SPLIT>
__global__ __launch_bounds__(256) void gemm_mfma_splitk(
    const float* __restrict__ A, const float* __restrict__ W,
    const float* __restrict__ bias, float* __restrict__ C,
    int M, int N, int K) {
  const int m0 = blockIdx.y * 128;
  const int n0 = blockIdx.x * 128;
  const int kbeg = blockIdx.z * (K / SPLIT);
  const int kend = kbeg + K / SPLIT;
  GEMM_PROLOGUE(K)
  for (int k0 = kbeg; k0 < kend; k0 += 32) GEMM_KSTEP(k0)

  const bool addb = (blockIdx.z == 0);
#pragma unroll
  for (int ni = 0; ni < 4; ++ni) {
    const int col = n0 + wn + ni * 16 + fr;
    const float bb = addb ? bias[col] : 0.f;
#pragma unroll
    for (int mi = 0; mi < 4; ++mi) {
      const int row = m0 + wm + mi * 16 + fc * 4;
#pragma unroll
      for (int j = 0; j < 4; ++j)
        atomicAdd(&C[(size_t)(row + j) * N + col], acc[mi][ni][j] + bb);
    }
  }
}

// ---------------------------------------------------------------------------
// In-place LayerNorm over rows of 512. One block (256 threads) per row.
// ---------------------------------------------------------------------------
__global__ __launch_bounds__(256) void layernorm_inplace(
    float* __restrict__ e, const float* __restrict__ g,
    const float* __restrict__ b) {
  const int row = blockIdx.x;
  float* x = e + (size_t)row * NU;
  const int tid = threadIdx.x;

  float2 v = *(const float2*)&x[tid * 2];
  float sum = v.x + v.y;
  float sq  = v.x * v.x + v.y * v.y;
#pragma unroll
  for (int o = 32; o > 0; o >>= 1) {
    sum += __shfl_down(sum, o);
    sq  += __shfl_down(sq, o);
  }
  __shared__ float ps[4], pq[4], stat[2];
  const int wid = tid >> 6, lane = tid & 63;
  if (lane == 0) { ps[wid] = sum; pq[wid] = sq; }
  __syncthreads();
  if (tid == 0) {
    float s = ps[0] + ps[1] + ps[2] + ps[3];
    float q = pq[0] + pq[1] + pq[2] + pq[3];
    float mu = s * (1.0f / NU);
    float var = q * (1.0f / NU) - mu * mu;
    stat[0] = mu;
    stat[1] = rsqrtf(var + 1e-5f);
  }
  __syncthreads();
  const float mu = stat[0], rstd = stat[1];
  const float2 gg = *(const float2*)&g[tid * 2];
  const float2 bb = *(const float2*)&b[tid * 2];
  v.x = (v.x - mu) * rstd * gg.x + bb.x;
  v.y = (v.y - mu) * rstd * gg.y + bb.y;
  *(float2*)&x[tid * 2] = v;
}

// ---------------------------------------------------------------------------
// MFMA flash attention (bf16 compute, fp32 accumulate).  (unchanged, verified)
// ---------------------------------------------------------------------------
__global__ __launch_bounds__(256) void flash_attn_mfma(
    const float* __restrict__ Q, const float* __restrict__ K,
    const float* __restrict__ V, float* __restrict__ O) {
  constexpr int LSTR = 72;
  __shared__ unsigned short Ks[64 * LSTR];   // [k][d]
  __shared__ unsigned short Vt[64 * LSTR];   // [d][k]  (transposed)
  __shared__ unsigned short Ps[128 * LSTR];  // [q][k]

  const int b = blockIdx.z, h = blockIdx.y;
  const int q0 = blockIdx.x * 128;
  const int tid = threadIdx.x;
  const int lane = tid & 63;
  const int w = tid >> 6;
  const int fr = lane & 15;
  const int fc = lane >> 4;

  const size_t hb = ((size_t)b * TT) * NU + h * DK;

  bf16x8 qf[2][2];
#pragma unroll
  for (int mi = 0; mi < 2; ++mi)
#pragma unroll
    for (int kc = 0; kc < 2; ++kc) {
      const float* qs = Q + hb + (size_t)(q0 + w * 32 + mi * 16 + fr) * NU + kc * 32 + fc * 8;
      float4 x0 = *(const float4*)qs;
      float4 x1 = *(const float4*)(qs + 4);
      qf[mi][kc] = cvt8(x0, x1, 0.125f);
    }

  f32x4 ctx[2][4];
#pragma unroll
  for (int mi = 0; mi < 2; ++mi)
#pragma unroll
    for (int ni = 0; ni < 4; ++ni) ctx[mi][ni] = (f32x4){0.f, 0.f, 0.f, 0.f};
  float m_run[2][4], l_run[2][4];
#pragma unroll
  for (int mi = 0; mi < 2; ++mi)
#pragma unroll
    for (int j = 0; j < 4; ++j) { m_run[mi][j] = -1e30f; l_run[mi][j] = 0.f; }

  const int sr = tid >> 2;
  const int sd = (tid & 3) * 16;

  for (int kt = 0; kt < TT; kt += 64) {
    const float* kp = K + hb + (size_t)(kt + sr) * NU + sd;
    const float* vp = V + hb + (size_t)(kt + sr) * NU + sd;
    float4 k0 = *(const float4*)kp,       k1 = *(const float4*)(kp + 4);
    float4 k2 = *(const float4*)(kp + 8), k3 = *(const float4*)(kp + 12);
    float4 v0 = *(const float4*)vp,       v1 = *(const float4*)(vp + 4);
    float4 v2 = *(const float4*)(vp + 8), v3 = *(const float4*)(vp + 12);

    __syncthreads();
    *(bf16x8*)&Ks[sr * LSTR + sd]     = cvt8(k0, k1, 1.f);
    *(bf16x8*)&Ks[sr * LSTR + sd + 8] = cvt8(k2, k3, 1.f);
    {
      float vv[16];
      *(float4*)&vv[0]  = v0; *(float4*)&vv[4]  = v1;
      *(float4*)&vv[8]  = v2; *(float4*)&vv[12] = v3;
#pragma unroll
      for (int t = 0; t < 16; ++t)
        Vt[(sd + t) * LSTR + sr] = f2b(vv[t]);
    }
    __syncthreads();

    bf16x8 kf[4][2];
#pragma unroll
    for (int ni = 0; ni < 4; ++ni)
#pragma unroll
      for (int kc = 0; kc < 2; ++kc)
        kf[ni][kc] = *(const bf16x8*)&Ks[(ni * 16 + fr) * LSTR + kc * 32 + fc * 8];

    f32x4 sacc[2][4];
#pragma unroll
    for (int mi = 0; mi < 2; ++mi)
#pragma unroll
      for (int ni = 0; ni < 4; ++ni) sacc[mi][ni] = (f32x4){0.f, 0.f, 0.f, 0.f};
#pragma unroll
    for (int kc = 0; kc < 2; ++kc)
#pragma unroll
      for (int mi = 0; mi < 2; ++mi)
#pragma unroll
        for (int ni = 0; ni < 4; ++ni)
          sacc[mi][ni] = __builtin_amdgcn_mfma_f32_16x16x32_bf16(
              qf[mi][kc], kf[ni][kc], sacc[mi][ni], 0, 0, 0);

#pragma unroll
    for (int mi = 0; mi < 2; ++mi) {
      float cm[4];
#pragma unroll
      for (int j = 0; j < 4; ++j)
        cm[j] = fmaxf(fmaxf(sacc[mi][0][j], sacc[mi][1][j]),
                      fmaxf(sacc[mi][2][j], sacc[mi][3][j]));
#pragma unroll
      for (int mask = 1; mask < 16; mask <<= 1)
#pragma unroll
        for (int j = 0; j < 4; ++j)
          cm[j] = fmaxf(cm[j], __shfl_xor(cm[j], mask));
#pragma unroll
      for (int j = 0; j < 4; ++j) {
        float mn = fmaxf(m_run[mi][j], cm[j]);
        float corr = __expf(m_run[mi][j] - mn);
        m_run[mi][j] = mn;
        l_run[mi][j] *= corr;
#pragma unroll
        for (int ni = 0; ni < 4; ++ni) {
          ctx[mi][ni][j] *= corr;
          float p = __expf(sacc[mi][ni][j] - mn);
          l_run[mi][j] += p;
          Ps[(w * 32 + mi * 16 + fc * 4 + j) * LSTR + ni * 16 + fr] = f2b(p);
        }
      }
    }

    bf16x8 pf[2][2], vf[4][2];
#pragma unroll
    for (int mi = 0; mi < 2; ++mi)
#pragma unroll
      for (int kc = 0; kc < 2; ++kc)
        pf[mi][kc] = *(const bf16x8*)&Ps[(w * 32 + mi * 16 + fr) * LSTR + kc * 32 + fc * 8];
#pragma unroll
    for (int ni = 0; ni < 4; ++ni)
#pragma unroll
      for (int kc = 0; kc < 2; ++kc)
        vf[ni][kc] = *(const bf16x8*)&Vt[(ni * 16 + fr) * LSTR + kc * 32 + fc * 8];
#pragma unroll
    for (int kc = 0; kc < 2; ++kc)
#pragma unroll
      for (int mi = 0; mi < 2; ++mi)
#pragma unroll
        for (int ni = 0; ni < 4; ++ni)
          ctx[mi][ni] = __builtin_amdgcn_mfma_f32_16x16x32_bf16(
              pf[mi][kc], vf[ni][kc], ctx[mi][ni], 0, 0, 0);
  }

#pragma unroll
  for (int mi = 0; mi < 2; ++mi)
#pragma unroll
    for (int j = 0; j < 4; ++j) {
      float l = l_run[mi][j];
#pragma unroll
      for (int mask = 1; mask < 16; mask <<= 1)
        l += __shfl_xor(l, mask);
      const float inv = 1.0f / l;
      const int row = q0 + w * 32 + mi * 16 + fc * 4 + j;
      float* dst = O + hb + (size_t)row * NU;
#pragma unroll
      for (int ni = 0; ni < 4; ++ni)
        dst[ni * 16 + fr] = ctx[mi][ni][j] * inv;
    }
}

// ---------------------------------------------------------------------------
// Launcher
// ---------------------------------------------------------------------------
extern "C" void kernel_launch(void* const* d_in, const int* in_sizes, int n_in,
                              void* d_out, int out_size, void* d_ws, size_t ws_size,
                              hipStream_t stream) {
  const float* x     = (const float*)d_in[0];
  const float* Win   = (const float*)d_in[1];
  const float* bin_  = (const float*)d_in[2];
  const float* ln1_g = (const float*)d_in[3];
  const float* ln1_b = (const float*)d_in[4];
  const float* Wq    = (const float*)d_in[5];
  const float* bq    = (const float*)d_in[6];
  const float* Wk    = (const float*)d_in[7];
  const float* bk    = (const float*)d_in[8];
  const float* Wv    = (const float*)d_in[9];
  const float* bv    = (const float*)d_in[10];
  const float* Wo    = (const float*)d_in[11];
  const float* bo    = (const float*)d_in[12];
  const float* ln2_g = (const float*)d_in[13];
  const float* ln2_b = (const float*)d_in[14];
  const float* W1    = (const float*)d_in[15];
  const float* b1    = (const float*)d_in[16];
  const float* W2    = (const float*)d_in[17];
  const float* b2    = (const float*)d_in[18];
  const float* lno_g = (const float*)d_in[19];
  const float* lno_b = (const float*)d_in[20];

  float* e = (float*)d_out;             // activation lives in d_out (8192x512)
  float* ws = (float*)d_ws;
  const size_t SLOT = (size_t)MTOT * NU;  // 4M floats = 16MB
  float* q   = ws;
  float* k   = ws + SLOT;
  float* v   = ws + 2 * SLOT;
  float* ctx = ws + 3 * SLOT;
  float* hdn = ws;                      // 8192x2048 fp32 = 64MB, all 4 slots

  const dim3 blk(256);
  const dim3 gProjIn(NU / 128, MTOT / 128);      // (4,64)   256 blocks
  const dim3 gQKV(NU / 128, MTOT / 128, 3);      // (4,64,3) 768 blocks
  const dim3 gWo(NU / 128, MTOT / 128, 2);       // (4,64,2) 512 blocks, split-K 2
  const dim3 gF1(EU / 128, MTOT / 128);          // (16,64)  1024 blocks
  const dim3 gF2(NU / 128, MTOT / 128, 4);       // (4,64,4) 1024 blocks, split-K 4
  const dim3 gAttn(TT / 128, NH, NB);            // (8,8,8)  512 blocks

  // input projection: e = x @ Win^T + bin
  gemm_mfma<false><<<gProjIn, blk, 0, stream>>>(x, Win, bin_, e, MTOT, NU, IDIM);

  for (int i = 0; i < NL; ++i) {
    const float* wq = Wq + (size_t)i * NU * NU;
    const float* wk = Wk + (size_t)i * NU * NU;
    const float* wv = Wv + (size_t)i * NU * NU;
    const float* wo = Wo + (size_t)i * NU * NU;
    const float* w1 = W1 + (size_t)i * EU * NU;
    const float* w2 = W2 + (size_t)i * NU * EU;

    // e = LN1(e)  (in place)
    layernorm_inplace<<<MTOT, blk, 0, stream>>>(e, ln1_g + i * NU, ln1_b + i * NU);

    // fused q,k,v projections
    gemm_qkv<<<gQKV, blk, 0, stream>>>(e, wq, wk, wv,
                                       bq + i * NU, bk + i * NU, bv + i * NU,
                                       q, k, v);

    // attention -> ctx
    flash_attn_mfma<<<gAttn, blk, 0, stream>>>(q, k, v, ctx);

    // e += ctx @ Wo^T + bo   (split-K 2, atomic accumulate)
    gemm_mfma_splitk<2><<<gWo, blk, 0, stream>>>(ctx, wo, bo + i * NU, e, MTOT, NU, NU);

    // e = LN2(e)
    layernorm_inplace<<<MTOT, blk, 0, stream>>>(e, ln2_g + i * NU, ln2_b + i * NU);

    // FFN, full M
    gemm_mfma<true><<<gF1, blk, 0, stream>>>(e, w1, b1 + i * EU, hdn, MTOT, EU, NU);
    gemm_mfma_splitk<4><<<gF2, blk, 0, stream>>>(hdn, w2, b2 + i * NU, e, MTOT, NU, EU);
  }

  // final LN (in place on d_out)
  layernorm_inplace<<<MTOT, blk, 0, stream>>>(e, lno_g, lno_b);
}

// Round 7
// 1040.793 us; speedup vs baseline: 3.9510x; 1.3450x over previous
//
#include <hip/hip_runtime.h>
#include <hip/hip_bf16.h>
#include <math.h>

// ---------------------------------------------------------------------------
// Problem constants
// ---------------------------------------------------------------------------
#define IDIM   256
#define NU     512
#define NL     4
#define EU     2048
#define NH     8
#define DK     64
#define TT     1024
#define NB     8
#define MTOT   8192

typedef short  bf16x8 __attribute__((ext_vector_type(8)));
typedef float  f32x4  __attribute__((ext_vector_type(4)));
typedef unsigned short ushortv2 __attribute__((ext_vector_type(2)));

// fp32 -> bf16 bits, round-to-nearest-even
__device__ __forceinline__ unsigned short f2b(float x) {
  unsigned int u = __float_as_uint(x);
  u += 0x7fffu + ((u >> 16) & 1u);
  return (unsigned short)(u >> 16);
}

// ---------------------------------------------------------------------------
// fp32 -> bf16 bulk convert (8 elems/thread)
// ---------------------------------------------------------------------------
__global__ __launch_bounds__(256) void cvt_bf16(
    const float* __restrict__ src, unsigned short* __restrict__ dst, int n) {
  int i = (blockIdx.x * 256 + threadIdx.x) * 8;
  if (i >= n) return;
  float4 a = *(const float4*)(src + i);
  float4 b = *(const float4*)(src + i + 4);
  bf16x8 r;
  r[0] = (short)f2b(a.x); r[1] = (short)f2b(a.y);
  r[2] = (short)f2b(a.z); r[3] = (short)f2b(a.w);
  r[4] = (short)f2b(b.x); r[5] = (short)f2b(b.y);
  r[6] = (short)f2b(b.z); r[7] = (short)f2b(b.w);
  *(bf16x8*)(dst + i) = r;
}

// ---------------------------------------------------------------------------
// bf16 MFMA GEMM core.  A[M,K], W[N,K] both bf16 row-major K-contiguous.
// BM=BN=128, BK=32, 4 waves (2x2), 4x4 16x16x32 frags.  LDS stride 40
// shorts (80B -> conflict-free b128 frag reads).  Register prefetch of the
// next K-step overlaps global loads with ds_read+MFMA.
// MODE: 0 = fp32 store, 1 = bf16 store, 2 = fp32 atomicAdd (split-K).
// ---------------------------------------------------------------------------
#define GEMM_CORE(K_, KBEG, KEND)                                            \
  constexpr int LSTR = 40;                                                   \
  __shared__ unsigned short As[128 * LSTR];                                  \
  __shared__ unsigned short Bs[128 * LSTR];                                  \
  const int tid  = threadIdx.x;                                              \
  const int lane = tid & 63;                                                 \
  const int wave = tid >> 6;                                                 \
  const int wm   = (wave >> 1) * 64;                                         \
  const int wn   = (wave & 1) * 64;                                          \
  const int fr   = lane & 15;                                                \
  const int fc   = lane >> 4;                                                \
  const int sr   = tid >> 1;                                                 \
  const int sh   = (tid & 1) * 16;                                           \
  const short* aptr = (const short*)A + (size_t)(m0 + sr) * (K_) + sh;       \
  const short* wptr = (const short*)W + (size_t)(n0 + sr) * (K_) + sh;       \
  short* asd = (short*)&As[sr * LSTR + sh];                                  \
  short* bsd = (short*)&Bs[sr * LSTR + sh];                                  \
  f32x4 acc[4][4];                                                           \
  _Pragma("unroll") for (int i = 0; i < 4; ++i)                              \
    _Pragma("unroll") for (int j = 0; j < 4; ++j)                            \
      acc[i][j] = (f32x4){0.f, 0.f, 0.f, 0.f};                               \
  bf16x8 pa0 = *(const bf16x8*)(aptr + (KBEG));                              \
  bf16x8 pa1 = *(const bf16x8*)(aptr + (KBEG) + 8);                          \
  bf16x8 pb0 = *(const bf16x8*)(wptr + (KBEG));                              \
  bf16x8 pb1 = *(const bf16x8*)(wptr + (KBEG) + 8);                          \
  for (int k0 = (KBEG); k0 < (KEND); k0 += 32) {                             \
    __syncthreads();                                                         \
    *(bf16x8*)asd = pa0;  *(bf16x8*)(asd + 8) = pa1;                         \
    *(bf16x8*)bsd = pb0;  *(bf16x8*)(bsd + 8) = pb1;                         \
    __syncthreads();                                                         \
    const int kn = k0 + 32;                                                  \
    if (kn < (KEND)) {  /* issue next-step loads before MFMA (overlap) */    \
      pa0 = *(const bf16x8*)(aptr + kn);                                     \
      pa1 = *(const bf16x8*)(aptr + kn + 8);                                 \
      pb0 = *(const bf16x8*)(wptr + kn);                                     \
      pb1 = *(const bf16x8*)(wptr + kn + 8);                                 \
    }                                                                        \
    bf16x8 af[4], bfr[4];                                                    \
    _Pragma("unroll") for (int mi = 0; mi < 4; ++mi)                         \
      af[mi] = *(const bf16x8*)&As[(wm + mi * 16 + fr) * LSTR + fc * 8];     \
    _Pragma("unroll") for (int ni = 0; ni < 4; ++ni)                         \
      bfr[ni] = *(const bf16x8*)&Bs[(wn + ni * 16 + fr) * LSTR + fc * 8];    \
    _Pragma("unroll") for (int mi = 0; mi < 4; ++mi)                         \
      _Pragma("unroll") for (int ni = 0; ni < 4; ++ni)                       \
        acc[mi][ni] = __builtin_amdgcn_mfma_f32_16x16x32_bf16(               \
            af[mi], bfr[ni], acc[mi][ni], 0, 0, 0);                          \
  }

template<int MODE, bool RELU>
__global__ __launch_bounds__(256) void gemm_bf(
    const unsigned short* __restrict__ A, const unsigned short* __restrict__ W,
    const float* __restrict__ bias, float* __restrict__ Cf,
    unsigned short* __restrict__ Cb, int M, int N, int K, int kchunk) {
  const int m0 = blockIdx.y * 128;
  const int n0 = blockIdx.x * 128;
  const int kbeg = blockIdx.z * kchunk;
  const int kend = kbeg + kchunk;
  GEMM_CORE(K, kbeg, kend)

  const bool addb = (blockIdx.z == 0);
#pragma unroll
  for (int ni = 0; ni < 4; ++ni) {
    const int col = n0 + wn + ni * 16 + fr;
    const float bb = (MODE != 2 || addb) ? bias[col] : 0.f;
#pragma unroll
    for (int mi = 0; mi < 4; ++mi) {
      const int row = m0 + wm + mi * 16 + fc * 4;
#pragma unroll
      for (int j = 0; j < 4; ++j) {
        size_t off = (size_t)(row + j) * N + col;
        float r = acc[mi][ni][j] + bb;
        if (RELU) r = fmaxf(r, 0.f);
        if (MODE == 0) Cf[off] = r;
        else if (MODE == 1) Cb[off] = f2b(r);
        else atomicAdd(&Cf[off], r);
      }
    }
  }
}

// Fused QKV: blockIdx.z picks (W,bias,out); q gets the 1/sqrt(dk) scale.
__global__ __launch_bounds__(256) void gemm_qkv(
    const unsigned short* __restrict__ A,
    const unsigned short* __restrict__ Wq, const unsigned short* __restrict__ Wk,
    const unsigned short* __restrict__ Wv,
    const float* __restrict__ bq, const float* __restrict__ bk,
    const float* __restrict__ bv,
    unsigned short* __restrict__ Oq, unsigned short* __restrict__ Ok,
    unsigned short* __restrict__ Ov) {
  const int zz = blockIdx.z;
  const unsigned short* W  = zz == 0 ? Wq : (zz == 1 ? Wk : Wv);
  const float* bias        = zz == 0 ? bq : (zz == 1 ? bk : bv);
  unsigned short* C        = zz == 0 ? Oq : (zz == 1 ? Ok : Ov);
  const float scale        = zz == 0 ? 0.125f : 1.0f;
  const int m0 = blockIdx.y * 128;
  const int n0 = blockIdx.x * 128;
  GEMM_CORE(NU, 0, NU)

#pragma unroll
  for (int ni = 0; ni < 4; ++ni) {
    const int col = n0 + wn + ni * 16 + fr;
    const float bb = bias[col];
#pragma unroll
    for (int mi = 0; mi < 4; ++mi) {
      const int row = m0 + wm + mi * 16 + fc * 4;
#pragma unroll
      for (int j = 0; j < 4; ++j)
        C[(size_t)(row + j) * NU + col] = f2b((acc[mi][ni][j] + bb) * scale);
    }
  }
}

// ---------------------------------------------------------------------------
// In-place LayerNorm (fp32), optional bf16 copy for GEMM consumption.
// ---------------------------------------------------------------------------
template<bool WB>
__global__ __launch_bounds__(256) void layernorm_inplace(
    float* __restrict__ e, const float* __restrict__ g,
    const float* __restrict__ b, unsigned short* __restrict__ eb) {
  const int row = blockIdx.x;
  float* x = e + (size_t)row * NU;
  const int tid = threadIdx.x;

  float2 v = *(const float2*)&x[tid * 2];
  float sum = v.x + v.y;
  float sq  = v.x * v.x + v.y * v.y;
#pragma unroll
  for (int o = 32; o > 0; o >>= 1) {
    sum += __shfl_down(sum, o);
    sq  += __shfl_down(sq, o);
  }
  __shared__ float ps[4], pq[4], stat[2];
  const int wid = tid >> 6, lane = tid & 63;
  if (lane == 0) { ps[wid] = sum; pq[wid] = sq; }
  __syncthreads();
  if (tid == 0) {
    float s = ps[0] + ps[1] + ps[2] + ps[3];
    float q = pq[0] + pq[1] + pq[2] + pq[3];
    float mu = s * (1.0f / NU);
    float var = q * (1.0f / NU) - mu * mu;
    stat[0] = mu;
    stat[1] = rsqrtf(var + 1e-5f);
  }
  __syncthreads();
  const float mu = stat[0], rstd = stat[1];
  const float2 gg = *(const float2*)&g[tid * 2];
  const float2 bb = *(const float2*)&b[tid * 2];
  v.x = (v.x - mu) * rstd * gg.x + bb.x;
  v.y = (v.y - mu) * rstd * gg.y + bb.y;
  *(float2*)&x[tid * 2] = v;
  if (WB) {
    ushortv2 o = {f2b(v.x), f2b(v.y)};
    *(ushortv2*)&eb[(size_t)row * NU + tid * 2] = o;
  }
}

// ---------------------------------------------------------------------------
// MFMA flash attention, bf16 in / bf16 out (q pre-scaled by 1/8).
// ---------------------------------------------------------------------------
__global__ __launch_bounds__(256) void flash_attn_mfma(
    const unsigned short* __restrict__ Q, const unsigned short* __restrict__ K,
    const unsigned short* __restrict__ V, unsigned short* __restrict__ O) {
  constexpr int LSTR = 72;
  __shared__ unsigned short Ks[64 * LSTR];   // [k][d]
  __shared__ unsigned short Vt[64 * LSTR];   // [d][k]
  __shared__ unsigned short Ps[128 * LSTR];  // [q][k]

  const int b = blockIdx.z, h = blockIdx.y;
  const int q0 = blockIdx.x * 128;
  const int tid = threadIdx.x;
  const int lane = tid & 63;
  const int w = tid >> 6;
  const int fr = lane & 15;
  const int fc = lane >> 4;

  const size_t hb = ((size_t)b * TT) * NU + h * DK;

  bf16x8 qf[2][2];
#pragma unroll
  for (int mi = 0; mi < 2; ++mi)
#pragma unroll
    for (int kc = 0; kc < 2; ++kc)
      qf[mi][kc] = *(const bf16x8*)(Q + hb +
          (size_t)(q0 + w * 32 + mi * 16 + fr) * NU + kc * 32 + fc * 8);

  f32x4 ctx[2][4];
#pragma unroll
  for (int mi = 0; mi < 2; ++mi)
#pragma unroll
    for (int ni = 0; ni < 4; ++ni) ctx[mi][ni] = (f32x4){0.f, 0.f, 0.f, 0.f};
  float m_run[2][4], l_run[2][4];
#pragma unroll
  for (int mi = 0; mi < 2; ++mi)
#pragma unroll
    for (int j = 0; j < 4; ++j) { m_run[mi][j] = -1e30f; l_run[mi][j] = 0.f; }

  const int sr = tid >> 2;
  const int sd = (tid & 3) * 16;

  for (int kt = 0; kt < TT; kt += 64) {
    const unsigned short* kp = K + hb + (size_t)(kt + sr) * NU + sd;
    const unsigned short* vp = V + hb + (size_t)(kt + sr) * NU + sd;
    bf16x8 k0 = *(const bf16x8*)kp, k1 = *(const bf16x8*)(kp + 8);
    bf16x8 v0 = *(const bf16x8*)vp, v1 = *(const bf16x8*)(vp + 8);

    __syncthreads();
    *(bf16x8*)&Ks[sr * LSTR + sd]     = k0;
    *(bf16x8*)&Ks[sr * LSTR + sd + 8] = k1;
#pragma unroll
    for (int t = 0; t < 8; ++t) {
      Vt[(sd + t)     * LSTR + sr] = (unsigned short)v0[t];
      Vt[(sd + t + 8) * LSTR + sr] = (unsigned short)v1[t];
    }
    __syncthreads();

    bf16x8 kf[4][2];
#pragma unroll
    for (int ni = 0; ni < 4; ++ni)
#pragma unroll
      for (int kc = 0; kc < 2; ++kc)
        kf[ni][kc] = *(const bf16x8*)&Ks[(ni * 16 + fr) * LSTR + kc * 32 + fc * 8];

    f32x4 sacc[2][4];
#pragma unroll
    for (int mi = 0; mi < 2; ++mi)
#pragma unroll
      for (int ni = 0; ni < 4; ++ni) sacc[mi][ni] = (f32x4){0.f, 0.f, 0.f, 0.f};
#pragma unroll
    for (int kc = 0; kc < 2; ++kc)
#pragma unroll
      for (int mi = 0; mi < 2; ++mi)
#pragma unroll
        for (int ni = 0; ni < 4; ++ni)
          sacc[mi][ni] = __builtin_amdgcn_mfma_f32_16x16x32_bf16(
              qf[mi][kc], kf[ni][kc], sacc[mi][ni], 0, 0, 0);

#pragma unroll
    for (int mi = 0; mi < 2; ++mi) {
      float cm[4];
#pragma unroll
      for (int j = 0; j < 4; ++j)
        cm[j] = fmaxf(fmaxf(sacc[mi][0][j], sacc[mi][1][j]),
                      fmaxf(sacc[mi][2][j], sacc[mi][3][j]));
#pragma unroll
      for (int mask = 1; mask < 16; mask <<= 1)
#pragma unroll
        for (int j = 0; j < 4; ++j)
          cm[j] = fmaxf(cm[j], __shfl_xor(cm[j], mask));
#pragma unroll
      for (int j = 0; j < 4; ++j) {
        float mn = fmaxf(m_run[mi][j], cm[j]);
        float corr = __expf(m_run[mi][j] - mn);
        m_run[mi][j] = mn;
        l_run[mi][j] *= corr;
#pragma unroll
        for (int ni = 0; ni < 4; ++ni) {
          ctx[mi][ni][j] *= corr;
          float p = __expf(sacc[mi][ni][j] - mn);
          l_run[mi][j] += p;
          Ps[(w * 32 + mi * 16 + fc * 4 + j) * LSTR + ni * 16 + fr] = f2b(p);
        }
      }
    }

    bf16x8 pf[2][2], vf[4][2];
#pragma unroll
    for (int mi = 0; mi < 2; ++mi)
#pragma unroll
      for (int kc = 0; kc < 2; ++kc)
        pf[mi][kc] = *(const bf16x8*)&Ps[(w * 32 + mi * 16 + fr) * LSTR + kc * 32 + fc * 8];
#pragma unroll
    for (int ni = 0; ni < 4; ++ni)
#pragma unroll
      for (int kc = 0; kc < 2; ++kc)
        vf[ni][kc] = *(const bf16x8*)&Vt[(ni * 16 + fr) * LSTR + kc * 32 + fc * 8];
#pragma unroll
    for (int kc = 0; kc < 2; ++kc)
#pragma unroll
      for (int mi = 0; mi < 2; ++mi)
#pragma unroll
        for (int ni = 0; ni < 4; ++ni)
          ctx[mi][ni] = __builtin_amdgcn_mfma_f32_16x16x32_bf16(
              pf[mi][kc], vf[ni][kc], ctx[mi][ni], 0, 0, 0);
  }

#pragma unroll
  for (int mi = 0; mi < 2; ++mi)
#pragma unroll
    for (int j = 0; j < 4; ++j) {
      float l = l_run[mi][j];
#pragma unroll
      for (int mask = 1; mask < 16; mask <<= 1)
        l += __shfl_xor(l, mask);
      const float inv = 1.0f / l;
      const int row = q0 + w * 32 + mi * 16 + fc * 4 + j;
      unsigned short* dst = O + hb + (size_t)row * NU;
#pragma unroll
      for (int ni = 0; ni < 4; ++ni)
        dst[ni * 16 + fr] = f2b(ctx[mi][ni][j] * inv);
    }
}

// ---------------------------------------------------------------------------
// Launcher.  ws (64MB) layout in bf16 units (1M = 1<<20 shorts):
//   [0,4M)q [4M,8M)k [8M,12M)v [12M,16M)ctx   --- hdn = [0,16M)
//   x_bf=[4M,6M) Win_bf=[6M,~) (dead before q/k/v written)
//   [16M,20M) e_bf
//   [20M,21M)Wq [21,22)Wk [22,23)Wv [23,24)Wo [24M,28M)W1 [28M,32M)W2
// ---------------------------------------------------------------------------
extern "C" void kernel_launch(void* const* d_in, const int* in_sizes, int n_in,
                              void* d_out, int out_size, void* d_ws, size_t ws_size,
                              hipStream_t stream) {
  const float* x     = (const float*)d_in[0];
  const float* Win   = (const float*)d_in[1];
  const float* bin_  = (const float*)d_in[2];
  const float* ln1_g = (const float*)d_in[3];
  const float* ln1_b = (const float*)d_in[4];
  const float* Wq    = (const float*)d_in[5];
  const float* bq    = (const float*)d_in[6];
  const float* Wk    = (const float*)d_in[7];
  const float* bk    = (const float*)d_in[8];
  const float* Wv    = (const float*)d_in[9];
  const float* bv    = (const float*)d_in[10];
  const float* Wo    = (const float*)d_in[11];
  const float* bo    = (const float*)d_in[12];
  const float* ln2_g = (const float*)d_in[13];
  const float* ln2_b = (const float*)d_in[14];
  const float* W1    = (const float*)d_in[15];
  const float* b1    = (const float*)d_in[16];
  const float* W2    = (const float*)d_in[17];
  const float* b2    = (const float*)d_in[18];
  const float* lno_g = (const float*)d_in[19];
  const float* lno_b = (const float*)d_in[20];

  float* e = (float*)d_out;
  unsigned short* wsb = (unsigned short*)d_ws;
  const size_t M1 = 1u << 20;
  unsigned short* q    = wsb;
  unsigned short* k    = wsb + 4 * M1;
  unsigned short* v    = wsb + 8 * M1;
  unsigned short* ctx  = wsb + 12 * M1;
  unsigned short* hdn  = wsb;                 // [0,16M)
  unsigned short* xbf  = wsb + 4 * M1;        // dead before k written
  unsigned short* winb = wsb + 6 * M1;
  unsigned short* ebf  = wsb + 16 * M1;
  unsigned short* wqb  = wsb + 20 * M1;
  unsigned short* wkb  = wsb + 21 * M1;
  unsigned short* wvb  = wsb + 22 * M1;
  unsigned short* wob  = wsb + 23 * M1;
  unsigned short* w1b  = wsb + 24 * M1;
  unsigned short* w2b  = wsb + 28 * M1;

  const dim3 blk(256);
  // one-time bf16 conversion of x + all weights
  cvt_bf16<<<1024, blk, 0, stream>>>(x,   xbf,  MTOT * IDIM);
  cvt_bf16<<<64,   blk, 0, stream>>>(Win, winb, NU * IDIM);
  cvt_bf16<<<512,  blk, 0, stream>>>(Wq,  wqb,  NL * NU * NU);
  cvt_bf16<<<512,  blk, 0, stream>>>(Wk,  wkb,  NL * NU * NU);
  cvt_bf16<<<512,  blk, 0, stream>>>(Wv,  wvb,  NL * NU * NU);
  cvt_bf16<<<512,  blk, 0, stream>>>(Wo,  wob,  NL * NU * NU);
  cvt_bf16<<<2048, blk, 0, stream>>>(W1,  w1b,  NL * EU * NU);
  cvt_bf16<<<2048, blk, 0, stream>>>(W2,  w2b,  NL * NU * EU);

  const dim3 gProjIn(NU / 128, MTOT / 128);      // 256 blocks
  const dim3 gQKV(NU / 128, MTOT / 128, 3);      // 768
  const dim3 gWo(NU / 128, MTOT / 128, 2);       // 512, split-K 2
  const dim3 gF1(EU / 128, MTOT / 128);          // 1024
  const dim3 gF2(NU / 128, MTOT / 128, 2);       // 512, split-K 2
  const dim3 gAttn(TT / 128, NH, NB);            // 512

  // e = x @ Win^T + bin   (fp32 out)
  gemm_bf<0, false><<<gProjIn, blk, 0, stream>>>(
      xbf, winb, bin_, e, nullptr, MTOT, NU, IDIM, IDIM);

  for (int i = 0; i < NL; ++i) {
    // LN1 -> e (fp32) + ebf (bf16)
    layernorm_inplace<true><<<MTOT, blk, 0, stream>>>(e, ln1_g + i * NU, ln1_b + i * NU, ebf);

    // q,k,v = ebf @ W^T + b  (bf16 out; q scaled by 1/8)
    gemm_qkv<<<gQKV, blk, 0, stream>>>(ebf, wqb + (size_t)i * NU * NU,
                                       wkb + (size_t)i * NU * NU,
                                       wvb + (size_t)i * NU * NU,
                                       bq + i * NU, bk + i * NU, bv + i * NU,
                                       q, k, v);

    flash_attn_mfma<<<gAttn, blk, 0, stream>>>(q, k, v, ctx);

    // e += ctx @ Wo^T + bo   (split-K 2, atomic)
    gemm_bf<2, false><<<gWo, blk, 0, stream>>>(
        ctx, wob + (size_t)i * NU * NU, bo + i * NU, e, nullptr,
        MTOT, NU, NU, NU / 2);

    // LN2 -> e + ebf
    layernorm_inplace<true><<<MTOT, blk, 0, stream>>>(e, ln2_g + i * NU, ln2_b + i * NU, ebf);

    // hdn = relu(ebf @ W1^T + b1)  (bf16 out)
    gemm_bf<1, true><<<gF1, blk, 0, stream>>>(
        ebf, w1b + (size_t)i * EU * NU, b1 + i * EU, nullptr, hdn,
        MTOT, EU, NU, NU);

    // e += hdn @ W2^T + b2   (split-K 2, atomic)
    gemm_bf<2, false><<<gF2, blk, 0, stream>>>(
        hdn, w2b + (size_t)i * NU * EU, b2 + i * NU, e, nullptr,
        MTOT, NU, EU, EU / 2);
  }

  layernorm_inplace<false><<<MTOT, blk, 0, stream>>>(e, lno_g, lno_b, nullptr);
}